// Round 14
// baseline (151.160 us; speedup 1.0000x reference)
//
#include <hip/hip_runtime.h>
#include <hip/hip_bf16.h>
#include <stdint.h>

// Problem constants
#define KK 4
#define BB 16
#define LL 4096
#define DD 512
#define HH 128

typedef __attribute__((ext_vector_type(8))) short bf16x8;
typedef __attribute__((ext_vector_type(4))) float f32x4;
typedef __attribute__((ext_vector_type(4))) unsigned int u32x4;

__device__ __forceinline__ unsigned int pack_bf16(float lo, float hi) {
  unsigned int a = __float_as_uint(lo);
  unsigned int b = __float_as_uint(hi);
  a = (a + 0x7FFFu + ((a >> 16) & 1u)) >> 16;   // RNE f32->bf16
  b = (b + 0x7FFFu + ((b >> 16) & 1u)) >> 16;
  return a | (b << 16);
}

// Raw barrier: LDS-ordering only (global loads stay in flight across it).
__device__ __forceinline__ void bar_lds() {
  __builtin_amdgcn_sched_barrier(0);
  asm volatile("s_waitcnt lgkmcnt(0)" ::: "memory");
  __builtin_amdgcn_s_barrier();
  __builtin_amdgcn_sched_barrier(0);
}

// Full-drain barrier: used once per tile, after a full tile of compute has
// separated the gload_lds issue from this wait (drain ~0 cycles).
__device__ __forceinline__ void bar_full() {
  __builtin_amdgcn_sched_barrier(0);
  asm volatile("s_waitcnt vmcnt(0) lgkmcnt(0)" ::: "memory");
  __builtin_amdgcn_s_barrier();
  __builtin_amdgcn_sched_barrier(0);
}

// x += row_shr:N (x) on the VALU pipe; rows of 16 lanes; 0-fill at row edge.
template <int N>
__device__ __forceinline__ float dpp_shr_add(float x) {
  int y = __builtin_amdgcn_update_dpp(0, __float_as_int(x), 0x110 | N, 0xF, 0xF,
                                      true);
  return x + __int_as_float(y);
}

__device__ __forceinline__ void load_lds16(const void* g, void* l) {
  // DMA 16B/lane: LDS dest = wave-uniform base + lane*16; global src per-lane.
  __builtin_amdgcn_global_load_lds(
      (const __attribute__((address_space(1))) unsigned int*)g,
      (__attribute__((address_space(3))) unsigned int*)l, 16, 0, 0);
}

// ---------------- kernel 0a: q_bias = W_q @ vq + ln_b ----------------
__global__ void qbias_kernel(const float* __restrict__ ln_w,
                             const float* __restrict__ ln_b,
                             const float* __restrict__ vq,
                             float* __restrict__ qb) {
  int h = threadIdx.x;
  if (h < HH) {
    float acc = ln_b[h];
    const float* wq = ln_w + (size_t)h * (DD + HH) + DD;
    for (int j = 0; j < HH; ++j) acc = fmaf(wq[j], vq[j], acc);
    qb[h] = acc;
  }
}

// ---------------- kernel 0b: W_h -> fragment-ordered bf16 (natural d) ----
// Chunk gid = (ks*8 + nt)*64 + lane holds 8 bf16 (MFMA B-fragment):
//   element j: W[nt*16 + (lane&15)][ks*32 + (lane>>4)*8 + j]
__global__ void wf_kernel(const float* __restrict__ ln_w,
                          unsigned int* __restrict__ wf) {
  int gid = blockIdx.x * 256 + threadIdx.x;   // 0..8191
  int ks = gid >> 9;
  int nt = (gid >> 6) & 7;
  int lane = gid & 63;
  int h = nt * 16 + (lane & 15);
  int d0 = ks * 32 + (lane >> 4) * 8;
  const float* src = ln_w + (size_t)h * (DD + HH) + d0;
  u32x4 v;
  v.x = pack_bf16(src[0], src[1]);
  v.y = pack_bf16(src[2], src[3]);
  v.z = pack_bf16(src[4], src[5]);
  v.w = pack_bf16(src[6], src[7]);
  *(u32x4*)(wf + (size_t)gid * 4) = v;
}

// ---------------- main fused kernel ----------------
// 256 blocks x 512 threads (1 block/CU, 8 waves), 32 tiles of 8 positions.
// A tile staged as *f32* in LDS (2 x 64KB dbuf) via global_load_lds DMA:
// issue pinned at tile start (sched_barrier), zero reg round-trip, zero
// wave involvement — the R4-R13 plateau is attributed to the compiler
// sinking reg-staged loads to their use point, emptying the read pipe.
// LDS layout: row = pos*4 + k (32 rows x 2KB), 32B-granule XOR swizzle
// physical = row*2048 + (logical ^ ((row&7)<<5)); source pre-swizzled.
// Cell map: wave wv -> st = wv&1 (rows st*16..+15), nt = {2(wv>>1), +1};
// f32 LDS read + in-reg pack to bf16 feeds MFMA. C/D: pos = st*4 + cg,
// k = reg j. Weighted sum reads f32 directly.
__global__ __launch_bounds__(512) void agg_main(
    const float* __restrict__ hs, const unsigned int* __restrict__ wf,
    const float* __restrict__ qb, const float* __restrict__ vw,
    float* __restrict__ out) {
  extern __shared__ char smem[];
  char* buf0 = smem;                             // 65536 B (32 rows x 2KB f32)
  char* buf1 = smem + 65536;                     // 65536 B
  f32x4* spv = (f32x4*)(smem + 131072);          // [8 pos][4 contrib] (k in vec)

  const int tid = threadIdx.x;
  const int lane = tid & 63;
  const int wv = tid >> 6;            // 0..7
  const int r = lane & 15;
  const int cg = lane >> 4;
  const int st = wv & 1;
  const int pr = wv >> 1;             // contributor index 0..3
  const int ntA = pr * 2, ntB = ntA + 1;

  const int b = blockIdx.x >> 4;
  const int l0b = (blockIdx.x & 15) << 8;        // 256 l per block, 32 tiles of 8

  // ---- W fragments for ntA, ntB (128 VGPR) ----
  bf16x8 wregA[16], wregB[16];
#pragma unroll
  for (int ks = 0; ks < 16; ++ks) {
    wregA[ks] = *(const bf16x8*)(wf + ((size_t)((ks * 8 + ntA) * 64 + lane)) * 4);
    wregB[ks] = *(const bf16x8*)(wf + ((size_t)((ks * 8 + ntB) * 64 + lane)) * 4);
  }

  const float qbrA = qb[ntA * 16 + r], qbrB = qb[ntB * 16 + r];
  const float vwrA = vw[ntA * 16 + r], vwrB = vw[ntB * 16 + r];

  // ---- DMA staging: 8 chunks/wave; chunk = wv*8+i -> row = chunk>>1,
  // half = chunk&1. Source byte pre-inverse-swizzled so LDS physical
  // layout carries the (row&7)<<5 XOR (rule #21: linear dest + swz src).
  auto issue_stage = [&](int l0, char* dst) {
#pragma unroll
    for (int i = 0; i < 8; ++i) {
      int chunk = wv * 8 + i;
      int row = chunk >> 1;
      int half = chunk & 1;
      int k = row & 3, pos = row >> 2;
      int gbyte = (half * 1024 + lane * 16) ^ ((row & 7) << 5);
      const char* p = (const char*)(hs +
          (((size_t)(k * BB + b)) * LL + l0 + pos) * DD) + gbyte;
      load_lds16(p, dst + chunk * 1024);
    }
    __builtin_amdgcn_sched_barrier(0);   // pin issue point: do not sink
  };

  // ---- prologue: stage tile 0 ----
  issue_stage(l0b, buf0);
  bar_full();

  for (int t = 0; t < 32; ++t) {
    const int l0 = l0b + t * 8;
    char* cur = (t & 1) ? buf1 : buf0;
    char* nxt = (t & 1) ? buf0 : buf1;

    // issue next tile's DMA NOW; it streams into LDS under this whole tile
    if (t < 31) issue_stage(l0 + 8, nxt);

    // ---- GEMM: 2 f32 ds_reads + pack + 2 MFMA per K-step ----
    f32x4 accA = {0.f, 0.f, 0.f, 0.f};
    f32x4 accB = {0.f, 0.f, 0.f, 0.f};
    const int abase = (st * 16 + r) * 2048;
    const int swz = (r & 7) << 5;
#pragma unroll
    for (int ks = 0; ks < 16; ++ks) {
      int off = (ks * 128 + cg * 32) ^ swz;
      f32x4 a0 = *(const f32x4*)(cur + abase + off);
      f32x4 a1 = *(const f32x4*)(cur + abase + off + 16);
      u32x4 pk;
      pk.x = pack_bf16(a0.x, a0.y);
      pk.y = pack_bf16(a0.z, a0.w);
      pk.z = pack_bf16(a1.x, a1.y);
      pk.w = pack_bf16(a1.z, a1.w);
      bf16x8 af = __builtin_bit_cast(bf16x8, pk);
      accA = __builtin_amdgcn_mfma_f32_16x16x32_bf16(af, wregA[ks], accA, 0, 0, 0);
      accB = __builtin_amdgcn_mfma_f32_16x16x32_bf16(af, wregB[ks], accB, 0, 0, 0);
    }

    // ---- scores: ps[k] = sum_h vw[h]*tanh(z+qb[h]) over this wave's 32 h ----
    float ps[4];
#pragma unroll
    for (int j = 0; j < 4; ++j) {
      float zA = accA[j] + qbrA;
      zA = fminf(15.f, fmaxf(-15.f, zA));
      float eA = __expf(-2.f * zA);
      float thA = (1.f - eA) * __builtin_amdgcn_rcpf(1.f + eA);
      float zB = accB[j] + qbrB;
      zB = fminf(15.f, fmaxf(-15.f, zB));
      float eB = __expf(-2.f * zB);
      float thB = (1.f - eB) * __builtin_amdgcn_rcpf(1.f + eB);
      ps[j] = fmaf(vwrA, thA, vwrB * thB);
    }
#pragma unroll
    for (int j = 0; j < 4; ++j) {
      ps[j] = dpp_shr_add<1>(ps[j]);
      ps[j] = dpp_shr_add<2>(ps[j]);
      ps[j] = dpp_shr_add<4>(ps[j]);
      ps[j] = dpp_shr_add<8>(ps[j]);
    }
    if (r == 15) {
      f32x4 v = {ps[0], ps[1], ps[2], ps[3]};
      spv[(st * 4 + cg) * 4 + pr] = v;   // pos = st*4+cg, contributor = pr
    }
    bar_lds();                        // B1: spv published (DMA stays in flight)

    // ---- softmax over k for pos = wv (4 broadcast reads) ----
    // mask dropped: uniform per-(b,l) shift is softmax-invariant
    float a0, a1, a2, a3;
    {
      f32x4 s = spv[wv * 4 + 0];
      s += spv[wv * 4 + 1];
      s += spv[wv * 4 + 2];
      s += spv[wv * 4 + 3];
      float mx = fmaxf(fmaxf(s.x, s.y), fmaxf(s.z, s.w));
      float e0 = __expf(s.x - mx), e1 = __expf(s.y - mx);
      float e2 = __expf(s.z - mx), e3 = __expf(s.w - mx);
      float inv = __builtin_amdgcn_rcpf(e0 + e1 + e2 + e3);
      a0 = e0 * inv; a1 = e1 * inv; a2 = e2 * inv; a3 = e3 * inv;
    }

    // ---- weighted sum: wave wv owns pos = wv; f32 reads from LDS ----
    {
      float x[8];
#pragma unroll
      for (int j = 0; j < 8; ++j) x[j] = 0.f;
#pragma unroll
      for (int k = 0; k < 4; ++k) {
        int row = wv * 4 + k;
        float ak = k == 0 ? a0 : (k == 1 ? a1 : (k == 2 ? a2 : a3));
        int off = (lane * 32) ^ ((row & 7) << 5);
        f32x4 v0 = *(const f32x4*)(cur + row * 2048 + off);
        f32x4 v1 = *(const f32x4*)(cur + row * 2048 + off + 16);
        x[0] = fmaf(ak, v0.x, x[0]);
        x[1] = fmaf(ak, v0.y, x[1]);
        x[2] = fmaf(ak, v0.z, x[2]);
        x[3] = fmaf(ak, v0.w, x[3]);
        x[4] = fmaf(ak, v1.x, x[4]);
        x[5] = fmaf(ak, v1.y, x[5]);
        x[6] = fmaf(ak, v1.z, x[6]);
        x[7] = fmaf(ak, v1.w, x[7]);
      }
      float* ob = out + (((size_t)b) * LL + l0 + wv) * DD + lane * 8;
      f32x4 o0 = {x[0], x[1], x[2], x[3]};
      f32x4 o1 = {x[4], x[5], x[6], x[7]};
      __builtin_nontemporal_store(o0, (f32x4*)ob);
      __builtin_nontemporal_store(o1, (f32x4*)(ob + 4));
    }

    // ---- tile-end: DMA for nxt has had a full tile to land; drain ~0 ----
    bar_full();                       // B2: buffer published
  }
}

extern "C" void kernel_launch(void* const* d_in, const int* in_sizes, int n_in,
                              void* d_out, int out_size, void* d_ws, size_t ws_size,
                              hipStream_t stream) {
  const float* hs   = (const float*)d_in[0];
  // d_in[1] = mask (int32) — unused: softmax over k is invariant to the
  // per-(b,l) uniform -1e4 shift, so the mask cannot affect x.
  const float* ln_w = (const float*)d_in[2];
  const float* ln_b = (const float*)d_in[3];
  const float* v_w  = (const float*)d_in[4];
  const float* vq   = (const float*)d_in[5];
  float* out = (float*)d_out;

  unsigned int* wf = (unsigned int*)d_ws;          // 128KB fragment-ordered bf16 W_h
  float* qb = (float*)((char*)d_ws + 131072);      // 512B q_bias

  qbias_kernel<<<1, 128, 0, stream>>>(ln_w, ln_b, vq, qb);
  wf_kernel<<<32, 256, 0, stream>>>(ln_w, wf);
  agg_main<<<256, 512, 131584, stream>>>(hs, wf, qb, v_w, out);
}